// Round 13
// baseline (27838.062 us; speedup 1.0000x reference)
//
#include <hip/hip_runtime.h>
#include <stdint.h>
#include <stddef.h>

#define T_STEPS 32768
#define HDIM    256
#define NTHR    256

typedef int v4i __attribute__((ext_vector_type(4)));

__device__ __forceinline__ float rcpf_(float x) {
#if defined(__has_builtin) && __has_builtin(__builtin_amdgcn_rcpf)
    return __builtin_amdgcn_rcpf(x);
#else
    return 1.0f / x;
#endif
}
// exact v_exp_f32: D = 2^S0
__device__ __forceinline__ float exp2f_(float x) {
    float r;
    asm("v_exp_f32 %0, %1" : "=v"(r) : "v"(x));
    return r;
}

// i8 MFMA 16x16x64: one wave-instr = 16 outputs x 64 k (exact i32 accum).
__device__ __forceinline__ v4i mfma8_(v4i a, v4i b, v4i c) {
#if defined(__has_builtin) && __has_builtin(__builtin_amdgcn_mfma_i32_16x16x64_i8)
    return __builtin_amdgcn_mfma_i32_16x16x64_i8(a, b, c, 0, 0, 0);
#else
    v4i d;
    asm("v_mfma_i32_16x16x64_i8 %0, %1, %2, %3"
        : "=a"(d) : "v"(a), "v"(b), "a"(c));
    return d;
#endif
}

__device__ __forceinline__ int sdot4_(uint32_t a, uint32_t b, int c) {
#if defined(__has_builtin) && __has_builtin(__builtin_amdgcn_sdot4)
    return __builtin_amdgcn_sdot4((int)a, (int)b, c, false);
#else
    int d;
    asm("v_dot4_i32_i8 %0, %1, %2, %3" : "=v"(d) : "v"(a), "v"(b), "v"(c));
    return d;
#endif
}

// float DPP add via row_shr (legal on CDNA4; row_bcast15/31 are NOT).
#define DPPADD(v, CTRL) { \
    int _s = __builtin_amdgcn_update_dpp(0, __builtin_bit_cast(int, v), \
                                         CTRL, 0xf, 0xf, true); \
    v += __builtin_bit_cast(float, _s); }

// |w_hh| <= 1/16 exactly -> fixed scale: q = rint(w * 127/0.0625)
__device__ __forceinline__ uint32_t packw4_(const float4 v) {
    int a = __float2int_rn(v.x * 2032.0f);
    int b = __float2int_rn(v.y * 2032.0f);
    int c = __float2int_rn(v.z * 2032.0f);
    int d = __float2int_rn(v.w * 2032.0f);
    return (uint32_t)(a & 255) | ((uint32_t)(b & 255) << 8) |
           ((uint32_t)(c & 255) << 16) | ((uint32_t)(d & 255) << 24);
}

// 8 named scalar weight dwords (32 int8 weights) per group (sdot4 side).
#define LWG(pref, G, P, B) \
    uint32_t pref##G##0 = packw4_((P)[(B) + 0]), \
             pref##G##1 = packw4_((P)[(B) + 1]), \
             pref##G##2 = packw4_((P)[(B) + 2]), \
             pref##G##3 = packw4_((P)[(B) + 3]), \
             pref##G##4 = packw4_((P)[(B) + 4]), \
             pref##G##5 = packw4_((P)[(B) + 5]), \
             pref##G##6 = packw4_((P)[(B) + 6]), \
             pref##G##7 = packw4_((P)[(B) + 7]);
#define PING(pref, G) asm volatile("" : \
    "+v"(pref##G##0), "+v"(pref##G##1), "+v"(pref##G##2), "+v"(pref##G##3), \
    "+v"(pref##G##4), "+v"(pref##G##5), "+v"(pref##G##6), "+v"(pref##G##7));

// 4 n-gate sdot4 into 4 rotating chains (fills one mfma's pipe time).
#define DN(G, D0, D1, D2, D3, HQ) \
    an0 = sdot4_(n##G##D0, (HQ).x, an0); \
    an1 = sdot4_(n##G##D1, (HQ).y, an1); \
    an2 = sdot4_(n##G##D2, (HQ).z, an2); \
    an3 = sdot4_(n##G##D3, (HQ).w, an3);

// 8 z-half sdot4 (one LWG group = 2 h-quads), 2 rotating chains.
#define DZ(G, HQA, HQB) \
    azs0 = sdot4_(zs##G##0, (HQA).x, azs0); azs1 = sdot4_(zs##G##1, (HQA).y, azs1); \
    azs0 = sdot4_(zs##G##2, (HQA).z, azs0); azs1 = sdot4_(zs##G##3, (HQA).w, azs1); \
    azs0 = sdot4_(zs##G##4, (HQB).x, azs0); azs1 = sdot4_(zs##G##5, (HQB).y, azs1); \
    azs0 = sdot4_(zs##G##6, (HQB).z, azs0); azs1 = sdot4_(zs##G##7, (HQB).w, azs1);

// R29 = R26 (19.03 champion) with a HYBRID dot engine. R27/R28 proved
// cross-wave MFMA||VALU on one SIMD is unwinnable from lockstep code; the
// untested concurrency is WITHIN-wave: issue independent sdot4s between
// the wave's own mfmas (AITER's MFMA<->load interleave, s02, with sdot4).
// Per wave the 192 row-dots cost 48 mfma (~765-980 pipe cyc) OR 192 sdot4
// (~790 issue cyc) — near-equal, so split: r via 16 mfma, z k0..127 via
// 8 mfma, z k128..255 via 32 sdot4, n via 64 sdot4 = 24 mfma (~490 pipe)
// + 96 sdot4 (~394 issue) interleaved 1:4 + sched_group_barrier ladder.
// All partials are exact ints summing to R26's totals -> absmax must stay
// exactly 0.0009765625. Worst case (no interleave) ~= R26 flat.
__global__ __launch_bounds__(NTHR)
void aether_gru_kernel(const float* __restrict__ xg,
                       const float* __restrict__ wih,
                       const float* __restrict__ whh,
                       const float* __restrict__ bih,
                       const float* __restrict__ bhh,
                       const float* __restrict__ wfc,
                       const float* __restrict__ bfc,
                       float* __restrict__ out,
                       float* __restrict__ pws_g) {
    const int tid  = threadIdx.x;
    const int lane = tid & 63;
    const int ri   = tid;                   // combine row 0..255 (= 64*wv+lane)
    const int rbase = (tid >> 6) << 6;      // wave row base 64w
    const int col  = lane & 15;             // chain col
    const int loff = (lane >> 4) << 4;      // k sub-offset within a k-tile

    __shared__ float xlds[T_STEPS + 2];
    __shared__ __align__(16) signed char hbuf[2][HDIM];
    __shared__ __align__(16) float pwsL[256 * 16];   // fc partial ring (16 KB)
    __shared__ float idxL[256];                      // event-index ring

    // ---- stage x into LDS (coalesced float4) ----
    {
        const float4* xs4 = (const float4*)xg;
        float4* xd4 = (float4*)xlds;
        #pragma unroll 4
        for (int i = 0; i < T_STEPS / 4 / NTHR; ++i)
            xd4[tid + NTHR * i] = xs4[tid + NTHR * i];
        if (tid == 0) { xlds[T_STEPS] = 0.0f; xlds[T_STEPS + 1] = 0.0f; }
    }

    // ---- MFMA B-fragments: r all 4 k-tiles, z k-tiles 0,1 only ----
#define LDB(NAME, g, c, kt) \
    v4i NAME; { \
        const float4* _r4 = (const float4*)(whh + \
            ((size_t)((g) * HDIM + rbase + 16 * (c) + col)) * HDIM + \
            64 * (kt) + loff); \
        NAME = (v4i){ (int)packw4_(_r4[0]), (int)packw4_(_r4[1]), \
                      (int)packw4_(_r4[2]), (int)packw4_(_r4[3]) }; }
    LDB(Br00,0,0,0) LDB(Br01,0,0,1) LDB(Br02,0,0,2) LDB(Br03,0,0,3)
    LDB(Br10,0,1,0) LDB(Br11,0,1,1) LDB(Br12,0,1,2) LDB(Br13,0,1,3)
    LDB(Br20,0,2,0) LDB(Br21,0,2,1) LDB(Br22,0,2,2) LDB(Br23,0,2,3)
    LDB(Br30,0,3,0) LDB(Br31,0,3,1) LDB(Br32,0,3,2) LDB(Br33,0,3,3)
    LDB(Bz00,1,0,0) LDB(Bz01,1,0,1)
    LDB(Bz10,1,1,0) LDB(Bz11,1,1,1)
    LDB(Bz20,1,2,0) LDB(Bz21,1,2,1)
    LDB(Bz30,1,3,0) LDB(Bz31,1,3,1)

    // ---- sdot4 weights (per-lane row ri): z k-dwords 32..63, n 0..63 ----
    const float4* pz4 = (const float4*)(whh + (size_t)(HDIM + ri) * HDIM);
    const float4* pn4 = (const float4*)(whh + (size_t)(2 * HDIM + ri) * HDIM);
    LWG(zs,A,pz4,32) LWG(zs,B,pz4,40) LWG(zs,C,pz4,48) LWG(zs,D,pz4,56)
    LWG(n,A,pn4,0)  LWG(n,B,pn4,8)  LWG(n,C,pn4,16) LWG(n,D,pn4,24)
    LWG(n,E,pn4,32) LWG(n,F,pn4,40) LWG(n,G,pn4,48) LWG(n,H,pn4,56)
    PING(zs,A) PING(zs,B) PING(zs,C) PING(zs,D)
    PING(n,A) PING(n,B) PING(n,C) PING(n,D)
    PING(n,E) PING(n,F) PING(n,G) PING(n,H)

    const v4i zero4 = {0, 0, 0, 0};

    // ---- per-row scalars (row = ri), exp2 (log2) domain — as R26 ----
    const float L1  = 1.4426950408889634f;           // log2(e)
    const float WSCALE = 0.0625f / 16129.0f;
    const float WSL  = WSCALE * L1;
    const float WSL2 = WSCALE * (2.0f * L1);
    const float wxr = wih[2 * ri] * L1,              wdr = wih[2 * ri + 1] * L1;
    const float wxz = wih[2 * (HDIM + ri)] * L1,     wdz = wih[2 * (HDIM + ri) + 1] * L1;
    const float wxn = wih[2 * (2*HDIM + ri)] * (2.0f*L1),
                wdn = wih[2 * (2*HDIM + ri) + 1] * (2.0f*L1);
    const float brc = (bih[ri] + bhh[ri]) * L1;
    const float bzc = (bih[HDIM + ri] + bhh[HDIM + ri]) * L1;
    const float bn2 = bih[2*HDIM + ri] * (2.0f*L1);
    const float cn2 = bhh[2*HDIM + ri] * (2.0f*L1);
    const float wf  = wfc[ri];
    const float bf  = bfc[0];

    if (tid < 64) ((float*)&hbuf[0][0])[tid] = 0.0f;   // zero h0
    __syncthreads();

    // ---- sequential state (uniform across threads -> uniform branches) ----
    float hprev    = 0.0f;
    float last_val = xlds[0] + 1.24f;       // xs[0] + (2*THRESHOLD + 1.0)
    float last_t   = 0.0f;
    int   cnt      = 0;
    int   cur      = 0;

    float xc = xlds[0];
    float xn = xlds[1];

    float* recon = out;
    float* idxp  = out + T_STEPS + 1;

    // prime A-fragments (per-lane) + h-quads (uniform, sdot4 side)
    const char* hbp = (const char*)&hbuf[0][0];
    v4i A0 = *(const v4i*)(hbp +   0 + loff);
    v4i A1 = *(const v4i*)(hbp +  64 + loff);
    v4i A2 = *(const v4i*)(hbp + 128 + loff);
    v4i A3 = *(const v4i*)(hbp + 192 + loff);
    const uint4* hu = (const uint4*)hbp;
    uint4 hq0 = hu[0],  hq1 = hu[1],  hq2 = hu[2],  hq3 = hu[3];
    uint4 hq4 = hu[4],  hq5 = hu[5],  hq6 = hu[6],  hq7 = hu[7];
    uint4 hq8 = hu[8],  hq9 = hu[9],  hq10 = hu[10], hq11 = hu[11];
    uint4 hq12 = hu[12], hq13 = hu[13], hq14 = hu[14], hq15 = hu[15];

    for (int t = 0; t < T_STEPS; ++t) {
        float xf = xlds[t + 2];                      // LDS prefetch, 2 ahead
        const float tf = (float)t;
        const bool ev = fabsf(xc - last_val) >= 0.12f;   // uniform

        if (ev) {
            const float dtv  = (tf - last_t) * 0.01f;
            const float gir  = fmaf(wxr, xc, fmaf(wdr, dtv, brc));
            const float giz  = fmaf(wxz, xc, fmaf(wdz, dtv, bzc));
            const float gin2 = fmaf(wxn, xc, fmaf(wdn, dtv, bn2));

            int an0 = 0, an1 = 0, an2 = 0, an3 = 0;
            int azs0 = 0, azs1 = 0;

            // ---- hybrid dot: 24 mfma (matrix pipe) interleaved with
            //      96 sdot4 (VALU) — each mfma's pipe time hides 4 dots.
            v4i aR0 = mfma8_(A0, Br00, zero4);  DN(A,0,1,2,3, hq0)
            v4i aR1 = mfma8_(A0, Br10, zero4);  DN(A,4,5,6,7, hq1)
            v4i aR2 = mfma8_(A0, Br20, zero4);  DN(B,0,1,2,3, hq2)
            v4i aR3 = mfma8_(A0, Br30, zero4);  DN(B,4,5,6,7, hq3)
            v4i aZ0 = mfma8_(A0, Bz00, zero4);  DN(C,0,1,2,3, hq4)
            v4i aZ1 = mfma8_(A0, Bz10, zero4);  DN(C,4,5,6,7, hq5)
            v4i aZ2 = mfma8_(A0, Bz20, zero4);  DN(D,0,1,2,3, hq6)
            v4i aZ3 = mfma8_(A0, Bz30, zero4);  DN(D,4,5,6,7, hq7)

            aR0 = mfma8_(A1, Br01, aR0);        DN(E,0,1,2,3, hq8)
            aR1 = mfma8_(A1, Br11, aR1);        DN(E,4,5,6,7, hq9)
            aR2 = mfma8_(A1, Br21, aR2);        DN(F,0,1,2,3, hq10)
            aR3 = mfma8_(A1, Br31, aR3);        DN(F,4,5,6,7, hq11)
            aZ0 = mfma8_(A1, Bz01, aZ0);        DN(G,0,1,2,3, hq12)
            aZ1 = mfma8_(A1, Bz11, aZ1);        DN(G,4,5,6,7, hq13)
            aZ2 = mfma8_(A1, Bz21, aZ2);        DN(H,0,1,2,3, hq14)
            aZ3 = mfma8_(A1, Bz31, aZ3);        DN(H,4,5,6,7, hq15)

            aR0 = mfma8_(A2, Br02, aR0);        DZ(A, hq8,  hq9)
            aR1 = mfma8_(A2, Br12, aR1);        DZ(B, hq10, hq11)
            aR2 = mfma8_(A2, Br22, aR2);
            aR3 = mfma8_(A2, Br32, aR3);
            aR0 = mfma8_(A3, Br03, aR0);        DZ(C, hq12, hq13)
            aR1 = mfma8_(A3, Br13, aR1);        DZ(D, hq14, hq15)
            aR2 = mfma8_(A3, Br23, aR2);
            aR3 = mfma8_(A3, Br33, aR3);

#if defined(__has_builtin) && __has_builtin(__builtin_amdgcn_sched_group_barrier)
            // enforce the 1 MFMA : 4 VALU interleave in the emitted stream
            #pragma unroll
            for (int i = 0; i < 24; ++i) {
                __builtin_amdgcn_sched_group_barrier(0x008, 1, 0); // 1 MFMA
                __builtin_amdgcn_sched_group_barrier(0x002, 4, 0); // 4 VALU
            }
#endif

            // ---- per-lane preact select: chain = lane>>4, col = lane&15.
            // D rows redundant (A broadcast) -> reg 0 valid. ----
            const bool c16 = (lane & 16) != 0;
            const bool c32 = (lane & 32) != 0;
            const int sr  = c32 ? (c16 ? aR3[0] : aR2[0])
                                : (c16 ? aR1[0] : aR0[0]);
            const int szm = c32 ? (c16 ? aZ3[0] : aZ2[0])
                                : (c16 ? aZ1[0] : aZ0[0]);
            const int sz = szm + (azs0 + azs1);          // exact int join
            const int sn = (an0 + an1) + (an2 + an3);

            // ---- combine (identical math to R26) ----
            const float prer = fmaf((float)sr, WSL, gir);
            const float prez = fmaf((float)sz, WSL, giz);
            const float hn2  = fmaf((float)sn, WSL2, cn2);
            const float r  = rcpf_(1.0f + exp2f_(-prer));
            const float zz = rcpf_(1.0f + exp2f_(-prez));
            const float e2 = exp2f_(fmaf(r, hn2, gin2));
            const float n  = fmaf(-2.0f, rcpf_(e2 + 1.0f), 1.0f);
            const float hnew = fmaf(zz, hprev - n, n);       // n + z(hp-n)
            hprev = hnew;

            // quantize + publish int8 h (row = ri = tid)
            hbuf[cur ^ 1][ri] = (signed char)__float2int_rn(hnew * 127.0f);

            float pv = hnew * wf;
            const int   slot = cnt & 255;
            const float tfe  = tf;
            last_val = xc;
            last_t   = tf;
            cnt++;

            __syncthreads();                 // ONE barrier: hbuf published
            cur ^= 1;
            {   // prefetch next event's A-fragments + h-quads (20 ds_reads;
                // consumed a full event later -> latency fully hidden)
                const char* hb2 = (const char*)&hbuf[cur][0];
                A0 = *(const v4i*)(hb2 +   0 + loff);
                A1 = *(const v4i*)(hb2 +  64 + loff);
                A2 = *(const v4i*)(hb2 + 128 + loff);
                A3 = *(const v4i*)(hb2 + 192 + loff);
                const uint4* hu2 = (const uint4*)hb2;
                hq0 = hu2[0];  hq1 = hu2[1];  hq2 = hu2[2];  hq3 = hu2[3];
                hq4 = hu2[4];  hq5 = hu2[5];  hq6 = hu2[6];  hq7 = hu2[7];
                hq8 = hu2[8];  hq9 = hu2[9];  hq10 = hu2[10]; hq11 = hu2[11];
                hq12 = hu2[12]; hq13 = hu2[13]; hq14 = hu2[14]; hq15 = hu2[15];
            }
#if defined(__has_builtin) && __has_builtin(__builtin_amdgcn_sched_barrier)
            __builtin_amdgcn_sched_barrier(0);   // don't sink the loads
#endif

            // ---- deferred fc tail: DPP row16 reduce -> LDS ring ----
            DPPADD(pv, 0x111)   // row_shr:1
            DPPADD(pv, 0x112)   // row_shr:2
            DPPADD(pv, 0x114)   // row_shr:4
            DPPADD(pv, 0x118)   // row_shr:8 -> lane15 of each row16 = sum
            if ((lane & 15) == 15) pwsL[(slot << 4) | (tid >> 4)] = pv;
            if (tid == 0) idxL[slot] = tfe;

            if (slot == 255) {               // flush full ring chunk (1/256)
                __syncthreads();             // ring writes -> visible
                const int ch = (cnt >> 8) - 1;
                float4* dst = (float4*)(pws_g + ((size_t)ch << 12));
                const float4* src = (const float4*)pwsL;
                dst[tid]       = src[tid];
                dst[tid + 256] = src[tid + 256];
                dst[tid + 512] = src[tid + 512];
                dst[tid + 768] = src[tid + 768];
                idxp[(ch << 8) + tid] = idxL[tid];
                __syncthreads();             // protect ring reuse
            }
        }

        xc = xn; xn = xf;
    }

    __syncthreads();    // make last ring writes visible to the flush

    // ---- flush remainder ----
    {
        const int rem  = cnt & 255;
        const int done = cnt - rem;
        if (rem) {
            for (int i = tid; i < (rem << 4); i += NTHR)
                pws_g[((size_t)done << 4) + i] = pwsL[i];
            if (tid < rem) idxp[done + tid] = idxL[tid];
        }
    }
    if (tid == 0) out[T_STEPS] = (float)cnt;          // n_events
    for (int i = cnt + tid; i < T_STEPS; i += NTHR)
        idxp[i] = 32768.0f;                           // pad with T
    __syncthreads();                                  // drain flush stores

    // ---- epilogue: pred per event + piecewise-constant recon fill ----
    for (int k = tid; k < cnt; k += NTHR) {
        const float4* s = (const float4*)(pws_g + ((size_t)k << 4));
        float4 a = s[0], b = s[1], c = s[2], d = s[3];
        float pred = ((a.x + a.y) + (a.z + a.w)) + ((b.x + b.y) + (b.z + b.w))
                   + ((c.x + c.y) + (c.z + c.w)) + ((d.x + d.y) + (d.z + d.w)) + bf;
        const int t0 = (int)idxp[k];
        const int t1 = (k + 1 < cnt) ? (int)idxp[k + 1] : T_STEPS;
        for (int t = t0; t < t1; ++t) recon[t] = pred;
    }
}

extern "C" void kernel_launch(void* const* d_in, const int* in_sizes, int n_in,
                              void* d_out, int out_size, void* d_ws, size_t ws_size,
                              hipStream_t stream) {
    const float* x    = (const float*)d_in[0];
    const float* wih  = (const float*)d_in[1];
    const float* whh  = (const float*)d_in[2];
    const float* bih  = (const float*)d_in[3];
    const float* bhh  = (const float*)d_in[4];
    const float* wfc  = (const float*)d_in[5];
    const float* bfc  = (const float*)d_in[6];
    float* out = (float*)d_out;
    float* pws = (float*)d_ws;   // <= 2 MB (30592 events x 64 B)

    hipLaunchKernelGGL(aether_gru_kernel, dim3(1), dim3(NTHR), 0, stream,
                       x, wih, whh, bih, bhh, wfc, bfc, out, pws);
}